// Round 8
// baseline (584.380 us; speedup 1.0000x reference)
//
#include <hip/hip_runtime.h>
#include <hip/hip_fp16.h>

typedef _Float16 f16;
typedef _Float16 f16x2 __attribute__((ext_vector_type(2)));
typedef _Float16 f16x8 __attribute__((ext_vector_type(8)));
typedef float f32x4 __attribute__((ext_vector_type(4)));
typedef unsigned u32x4 __attribute__((ext_vector_type(4)));

// Combined projection: rows 0..511 = Wq (8 heads x 64), 512..1023 = Wk,
// 1024..1055 = Ww (V), 1056..1311 = Wb (output). Padded to 1408 rows (128-mult).
#define WC_ROWS 1312
#define WC_PAD 1408

// ---------------- prep: combined weight matrix (f16) + bias (f32) ----------------
__global__ void prep_weights(const float* __restrict__ Wq, const float* __restrict__ bq,
                             const float* __restrict__ Wk, const float* __restrict__ bk,
                             const float* __restrict__ Ww, const float* __restrict__ bw,
                             const float* __restrict__ Wb, const float* __restrict__ bb,
                             f16* __restrict__ Wc, float* __restrict__ bias) {
    int id = blockIdx.x * 256 + threadIdx.x;   // WC_PAD*256 threads
    int j = id >> 8, k = id & 255;
    if (j >= WC_PAD) return;
    float v;
    if (j < 512)       v = Wq[j*256 + k];          // Wq flat [8,64,256]: row h*64+d == j
    else if (j < 1024) v = Wk[(j-512)*256 + k];
    else if (j < 1056) v = Ww[(j-1024)*256 + k];
    else if (j < 1312) v = Wb[(j-1056)*256 + k];
    else               v = 0.f;
    Wc[j*256 + k] = (f16)v;
    if (k == 0) {
        float b;
        if (j < 512)       b = bq[j];
        else if (j < 1024) b = bk[j-512];
        else if (j < 1056) b = bw[j-1024];
        else if (j < 1312) b = bb[j-1056];
        else               b = 0.f;
        bias[j] = b;
    }
}

// ---------------- prep: CSR row starts (edges sorted by src; every row non-empty) --
__global__ void build_rows(const int* __restrict__ src, int E, int n, int* __restrict__ rs) {
    int e = blockIdx.x * 256 + threadIdx.x;
    if (e == 0) rs[n] = E;
    if (e < E) {
        if (e == 0 || src[e] != src[e-1]) rs[src[e]] = e;
    }
}

// ---------------- fused projection GEMM (reads f32 features, converts inline) -----
// C[m][g] = sum_k F[m][k] * Wc[g][k] + bias[g];  scatter by g-region.
// Tile 128x128, BK=32, 4 waves (2x2, 64x64 each), mfma_f32_16x16x32_f16.
__device__ __forceinline__ int swz_slot(int row, int c) {
    return row * 4 + (c ^ (row & 3) ^ ((row >> 2) & 3));
}

__device__ __forceinline__ uint4 cvt8(float4 a, float4 b) {
    f16x8 o;
    o[0] = (f16)a.x; o[1] = (f16)a.y; o[2] = (f16)a.z; o[3] = (f16)a.w;
    o[4] = (f16)b.x; o[5] = (f16)b.y; o[6] = (f16)b.z; o[7] = (f16)b.w;
    return __builtin_bit_cast(uint4, o);
}

__launch_bounds__(256)
__global__ void gemm_fused(const float* __restrict__ F, const f16* __restrict__ Wc,
                           const float* __restrict__ bias,
                           f16* __restrict__ Qb, f16* __restrict__ Kb, f16* __restrict__ Vb,
                           float* __restrict__ Out, int n) {
    __shared__ uint4 As4[512];   // 128 rows x 32 k (f16) = 8KB
    __shared__ uint4 Bs4[512];   // 128 rows x 32 k = 8KB
    int t = threadIdx.x;
    int lane = t & 63, w = t >> 6;
    int wm = w >> 1, wn = w & 1;
    long m0 = (long)blockIdx.y * 128;
    int n0 = blockIdx.x * 128;

    f32x4 acc[4][4];
    #pragma unroll
    for (int i = 0; i < 4; i++)
        #pragma unroll
        for (int j = 0; j < 4; j++)
            acc[i][j] = (f32x4){0.f, 0.f, 0.f, 0.f};

    int lrow = t >> 2, lc = t & 3;
    long row0 = m0 + lrow, row1 = m0 + 64 + lrow;
    const float4* Fg0 = (const float4*)(F + row0 * 256 + lc * 8);   // 8 f32 per thread
    const float4* Fg1 = (const float4*)(F + row1 * 256 + lc * 8);
    const uint4*  Bg0 = (const uint4*)(Wc + (long)(n0 + lrow) * 256 + lc * 8);
    const uint4*  Bg1 = (const uint4*)(Wc + (long)(n0 + 64 + lrow) * 256 + lc * 8);
    bool ok0 = row0 < n, ok1 = row1 < n;
    int ws0 = swz_slot(lrow, lc);
    int ws1 = swz_slot(lrow + 64, lc);
    int csw = (lane >> 4) ^ (lane & 3) ^ ((lane >> 2) & 3);
    int arow = wm * 64 + (lane & 15);
    int brow = wn * 64 + (lane & 15);

    float4 fa0 = {}, fb0 = {}, fa1 = {}, fb1 = {};
    if (ok0) { fa0 = Fg0[0]; fb0 = Fg0[1]; }
    if (ok1) { fa1 = Fg1[0]; fb1 = Fg1[1]; }
    uint4 rb0 = Bg0[0], rb1 = Bg1[0];
    for (int kt = 0; kt < 8; ++kt) {
        if (kt) __syncthreads();
        As4[ws0] = cvt8(fa0, fb0);
        As4[ws1] = cvt8(fa1, fb1);
        Bs4[ws0] = rb0;
        Bs4[ws1] = rb1;
        __syncthreads();
        if (kt < 7) {            // prefetch next K-slice (k step 32 f32 = 8 float4)
            if (ok0) { fa0 = Fg0[(kt + 1) * 8]; fb0 = Fg0[(kt + 1) * 8 + 1]; }
            if (ok1) { fa1 = Fg1[(kt + 1) * 8]; fb1 = Fg1[(kt + 1) * 8 + 1]; }
            rb0 = Bg0[(kt + 1) * 4];
            rb1 = Bg1[(kt + 1) * 4];
        }
        f16x8 af[4], bf[4];
        const f16x8* Ap = (const f16x8*)As4;
        const f16x8* Bp = (const f16x8*)Bs4;
        #pragma unroll
        for (int i = 0; i < 4; i++) af[i] = Ap[(arow + i * 16) * 4 + csw];
        #pragma unroll
        for (int j = 0; j < 4; j++) bf[j] = Bp[(brow + j * 16) * 4 + csw];
        #pragma unroll
        for (int i = 0; i < 4; i++)
            #pragma unroll
            for (int j = 0; j < 4; j++)
                acc[i][j] = __builtin_amdgcn_mfma_f32_16x16x32_f16(af[i], bf[j], acc[i][j], 0, 0, 0);
    }

    // epilogue: C row = (lane>>4)*4 + reg (M), col = lane&15 (N)  [m89-verified]
    #pragma unroll
    for (int i = 0; i < 4; i++) {
        long gmb = m0 + wm * 64 + i * 16 + (lane >> 4) * 4;
        #pragma unroll
        for (int j = 0; j < 4; j++) {
            int gn = n0 + wn * 64 + j * 16 + (lane & 15);
            float bv = bias[gn];
            #pragma unroll
            for (int r = 0; r < 4; r++) {
                long gm = gmb + r;
                if (gm >= n) continue;
                float v = acc[i][j][r] + bv;
                if (gn < 512)       Qb[gm * 512 + gn] = (f16)v;
                else if (gn < 1024) Kb[gm * 512 + (gn - 512)] = (f16)v;
                else if (gn < 1056) Vb[gm * 32 + (gn - 1024)] = (f16)v;
                else if (gn < 1312) Out[gm * 256 + (gn - 1056)] = v;
                // gn in [1312,1408): padding, no write
            }
        }
    }
}

// ---------------- f16x2 dot helper ----------------
__device__ __forceinline__ float fd2(unsigned a, unsigned b, float c) {
#if defined(__has_builtin)
#if __has_builtin(__builtin_amdgcn_fdot2)
    return __builtin_amdgcn_fdot2(__builtin_bit_cast(f16x2, a), __builtin_bit_cast(f16x2, b), c, false);
#else
    f16x2 x = __builtin_bit_cast(f16x2, a), y = __builtin_bit_cast(f16x2, b);
    return c + (float)x[0] * (float)y[0] + (float)x[1] * (float)y[1];
#endif
#else
    f16x2 x = __builtin_bit_cast(f16x2, a), y = __builtin_bit_cast(f16x2, b);
    return c + (float)x[0] * (float)y[0] + (float)x[1] * (float)y[1];
#endif
}

// ---------------- phase A: edge-parallel scores ----------------
// 8 lanes per edge (lane = head). K is the fundamental random gather and the L2
// is its only amplifier (hit ~57% at round 6). Q / edge-list / sE have NO L2
// reuse (Q's window is L1-resident; sE consumed a kernel later) -> mark them
// non-temporal so the L2 capacity is dedicated to K lines.
__launch_bounds__(256)
__global__ void edge_scores(const int* __restrict__ srcA, const int* __restrict__ dstA,
                            const f16* __restrict__ Qb, const f16* __restrict__ Kb,
                            f16* __restrict__ sE, int E, int nwg) {
    int bid = blockIdx.x;
    int q = nwg >> 3, r = nwg & 7, xcd = bid & 7, off = bid >> 3;
    int wg = (xcd < r ? xcd * (q + 1) : r * (q + 1) + (xcd - r) * q) + off;
    long id = (long)wg * 256 + threadIdx.x;
    int e = (int)(id >> 3), h = (int)(id & 7);
    if (e >= E) return;
    int s = __builtin_nontemporal_load(srcA + e);
    int d = __builtin_nontemporal_load(dstA + e);
    const uint4* kp = (const uint4*)(Kb + (size_t)d * 512 + h * 64);
    const u32x4* qp = (const u32x4*)(Qb + (size_t)s * 512 + h * 64);
    uint4 kv[8];
    u32x4 qv[8];
    #pragma unroll
    for (int c = 0; c < 8; c++) kv[c] = kp[c];   // random gather: L2-cached (the win)
    #pragma unroll
    for (int c = 0; c < 8; c++)
        asm volatile("" : "+v"(kv[c].x), "+v"(kv[c].y), "+v"(kv[c].z), "+v"(kv[c].w));
    #pragma unroll
    for (int c = 0; c < 8; c++) qv[c] = __builtin_nontemporal_load(qp + c);  // L1-window only
    float a0 = 0.f, a1 = 0.f;
    #pragma unroll
    for (int c = 0; c < 8; c += 2) {
        a0 = fd2(qv[c][0],   kv[c].x,   a0);
        a0 = fd2(qv[c][1],   kv[c].y,   a0);
        a0 = fd2(qv[c][2],   kv[c].z,   a0);
        a0 = fd2(qv[c][3],   kv[c].w,   a0);
        a1 = fd2(qv[c+1][0], kv[c+1].x, a1);
        a1 = fd2(qv[c+1][1], kv[c+1].y, a1);
        a1 = fd2(qv[c+1][2], kv[c+1].z, a1);
        a1 = fd2(qv[c+1][3], kv[c+1].w, a1);
    }
    f16 res = (f16)(a0 + a1);
    __builtin_nontemporal_store(res, sE + (size_t)e * 8 + h);   // no L2 pollution
}

// ---------------- phase B: row-parallel softmax + MFMA aggregation ----------------
// Wave per row. Pass 1: per-head max. Pass 2: P = exp(s-m) -> LDS (XOR-swizzled);
// out[16h x 32d] = P @ Vgather via 4 MFMAs; denom l = P @ ones via 2 more MFMAs.
__launch_bounds__(256)
__global__ void edge_agg(const int* __restrict__ rs, const int* __restrict__ dstA,
                         const f16* __restrict__ sE, const f16* __restrict__ Vb,
                         float* __restrict__ Out, int n) {
    __shared__ __align__(16) f16 P_lds[4][16][64];
    __shared__ int dS[4][64];
    int w = threadIdx.x >> 6, lane = threadIdx.x & 63;
    int row = blockIdx.x * 4 + w;
    if (row >= n) return;
    int e0 = rs[row], deg = rs[row + 1] - e0;
    {   // zero A-frag rows 8..15 (read by MFMA, results discarded; avoid NaN garbage)
        f16x8 z = {};
        *(f16x8*)&P_lds[w][8 + (lane >> 3)][(lane & 7) * 8] = z;
    }
    // pass 1: global per-head max
    float pm[8];
    #pragma unroll
    for (int h = 0; h < 8; h++) pm[h] = -1e30f;
    for (int base = 0; base < deg; base += 64) {
        bool act = lane < deg - base;
        f16x8 s8 = {};
        if (act) s8 = *(const f16x8*)(sE + (size_t)(e0 + base + lane) * 8);
        #pragma unroll
        for (int h = 0; h < 8; h++)
            pm[h] = fmaxf(pm[h], act ? (float)s8[h] : -1e30f);
    }
    float m[8];
    #pragma unroll
    for (int h = 0; h < 8; h++) {
        float v = pm[h];
        #pragma unroll
        for (int off = 1; off < 64; off <<= 1) v = fmaxf(v, __shfl_xor(v, off));
        m[h] = v;
    }
    // pass 2: P, V-MFMA, ones-MFMA (denominator)
    f32x4 acc0 = {}, acc1 = {}, accl = {};
    int ec0 = (lane >> 4) * 8, h_a = lane & 15, hsel = (lane >> 4) & 1;
    f16x8 ones;
    #pragma unroll
    for (int j = 0; j < 8; j++) ones[j] = (f16)1.f;
    for (int base = 0; base < deg; base += 64) {
        int nE = deg - base; if (nE > 64) nE = 64;
        bool act = lane < nE;
        int d = dstA[e0 + base + (act ? lane : 0)];
        dS[w][lane] = d;
        f16x8 s8 = {};
        if (act) s8 = *(const f16x8*)(sE + (size_t)(e0 + base + lane) * 8);
        #pragma unroll
        for (int h = 0; h < 8; h++) {
            float p = act ? __expf((float)s8[h] - m[h]) : 0.f;
            P_lds[w][h][lane ^ (h << 3)] = (f16)p;
        }
        // A-frags: P[h][k], k = ks*32 + ec0 + j (XOR-decoded contiguous b128)
        f16x8 a0 = *(const f16x8*)&P_lds[w][h_a][(ec0)      ^ ((h_a & 7) << 3)];
        f16x8 a1 = *(const f16x8*)&P_lds[w][h_a][(32 + ec0) ^ ((h_a & 7) << 3)];
        // B-frags: V[e][dim], dim = nh*16 + (lane&15)
        f16x8 bf0a, bf0b, bf1a, bf1b;
        #pragma unroll
        for (int j = 0; j < 8; j++) {
            int dd0 = dS[w][ec0 + j];
            int dd1 = dS[w][32 + ec0 + j];
            const f16* vp0 = Vb + (size_t)dd0 * 32 + (lane & 15);
            const f16* vp1 = Vb + (size_t)dd1 * 32 + (lane & 15);
            bf0a[j] = vp0[0];  bf0b[j] = vp0[16];
            bf1a[j] = vp1[0];  bf1b[j] = vp1[16];
        }
        acc0 = __builtin_amdgcn_mfma_f32_16x16x32_f16(a0, bf0a, acc0, 0, 0, 0);
        acc0 = __builtin_amdgcn_mfma_f32_16x16x32_f16(a1, bf1a, acc0, 0, 0, 0);
        acc1 = __builtin_amdgcn_mfma_f32_16x16x32_f16(a0, bf0b, acc1, 0, 0, 0);
        acc1 = __builtin_amdgcn_mfma_f32_16x16x32_f16(a1, bf1b, acc1, 0, 0, 0);
        accl = __builtin_amdgcn_mfma_f32_16x16x32_f16(a0, ones, accl, 0, 0, 0);
        accl = __builtin_amdgcn_mfma_f32_16x16x32_f16(a1, ones, accl, 0, 0, 0);
    }
    // epilogue: D row = hsel*4 + r = head, col = lane&15; out dim = h*32 + nh*16 + col
    if (lane < 32) {
        float* op = Out + (size_t)row * 256 + (lane & 15);
        #pragma unroll
        for (int r = 0; r < 4; r++) {
            int h = hsel * 4 + r;
            float inv = 1.f / accl[r];
            float* p0 = op + h * 32;
            float* p1 = op + h * 32 + 16;
            float v0 = __builtin_nontemporal_load(p0) + acc0[r] * inv;
            float v1 = __builtin_nontemporal_load(p1) + acc1[r] * inv;
            __builtin_nontemporal_store(v0, p0);
            __builtin_nontemporal_store(v1, p1);
        }
    }
}

// ---------------- launch ----------------
extern "C" void kernel_launch(void* const* d_in, const int* in_sizes, int n_in,
                              void* d_out, int out_size, void* d_ws, size_t ws_size,
                              hipStream_t stream) {
    const float* F  = (const float*)d_in[0];
    const int*   ei = (const int*)d_in[1];
    const float* Wq = (const float*)d_in[2];
    const float* bq = (const float*)d_in[3];
    const float* Wk = (const float*)d_in[4];
    const float* bk = (const float*)d_in[5];
    const float* Ww = (const float*)d_in[6];
    const float* bw = (const float*)d_in[7];
    const float* Wb = (const float*)d_in[8];
    const float* bb = (const float*)d_in[9];
    int n = in_sizes[0] / 256;       // 50000
    int E = in_sizes[1] / 2;
    const int* srcA = ei;
    const int* dstA = ei + E;
    int n_pad = (n + 127) & ~127;

    // workspace carve-out (~133 MB)
    char* wp = (char*)d_ws;
    auto alloc = [&](size_t bytes) { void* p = wp; wp += (bytes + 255) & ~255ull; return p; };
    f16*   sE   = (f16*)alloc((size_t)E * 8 * 2);
    f16*   Wc   = (f16*)alloc((size_t)WC_PAD * 256 * 2);
    float* bias = (float*)alloc((size_t)WC_PAD * 4);
    f16*   Qb   = (f16*)alloc((size_t)n * 512 * 2);
    f16*   Kb   = (f16*)alloc((size_t)n * 512 * 2);
    f16*   Vb   = (f16*)alloc((size_t)n * 32 * 2);
    int*   rs   = (int*)alloc((size_t)(n + 1) * 4);
    float* Out  = (float*)d_out;

    prep_weights<<<WC_PAD, 256, 0, stream>>>(Wq, bq, Wk, bk, Ww, bw, Wb, bb, Wc, bias);
    build_rows<<<(E + 255) / 256, 256, 0, stream>>>(srcA, E, n, rs);
    dim3 g(WC_PAD / 128, n_pad / 128);   // N fastest: A-panel L2-reuse, B L2-resident
    gemm_fused<<<g, 256, 0, stream>>>(F, Wc, bias, Qb, Kb, Vb, Out, n);
    int nwg = (int)(((long)E * 8 + 255) / 256);
    edge_scores<<<nwg, 256, 0, stream>>>(srcA, dstA, Qb, Kb, sE, E, nwg);
    edge_agg<<<(n + 3) / 4, 256, 0, stream>>>(rs, dstA, sE, Vb, Out, n);
}

// Round 9
// 537.074 us; speedup vs baseline: 1.0881x; 1.0881x over previous
//
#include <hip/hip_runtime.h>
#include <hip/hip_fp16.h>

typedef _Float16 f16;
typedef _Float16 f16x2 __attribute__((ext_vector_type(2)));
typedef _Float16 f16x4v __attribute__((ext_vector_type(4)));
typedef _Float16 f16x8 __attribute__((ext_vector_type(8)));
typedef float f32x4 __attribute__((ext_vector_type(4)));

// Combined projection: rows 0..511 = Wq (8 heads x 64), 512..1023 = Wk,
// 1024..1055 = Ww (V), 1056..1311 = Wb (output). Padded to 1408 rows (128-mult).
#define WC_ROWS 1312
#define WC_PAD 1408

// ---------------- prep: combined weight matrix (f16) + bias (f32) ----------------
__global__ void prep_weights(const float* __restrict__ Wq, const float* __restrict__ bq,
                             const float* __restrict__ Wk, const float* __restrict__ bk,
                             const float* __restrict__ Ww, const float* __restrict__ bw,
                             const float* __restrict__ Wb, const float* __restrict__ bb,
                             f16* __restrict__ Wc, float* __restrict__ bias) {
    int id = blockIdx.x * 256 + threadIdx.x;   // WC_PAD*256 threads
    int j = id >> 8, k = id & 255;
    if (j >= WC_PAD) return;
    float v;
    if (j < 512)       v = Wq[j*256 + k];          // Wq flat [8,64,256]: row h*64+d == j
    else if (j < 1024) v = Wk[(j-512)*256 + k];
    else if (j < 1056) v = Ww[(j-1024)*256 + k];
    else if (j < 1312) v = Wb[(j-1056)*256 + k];
    else               v = 0.f;
    Wc[j*256 + k] = (f16)v;
    if (k == 0) {
        float b;
        if (j < 512)       b = bq[j];
        else if (j < 1024) b = bk[j-512];
        else if (j < 1056) b = bw[j-1024];
        else if (j < 1312) b = bb[j-1056];
        else               b = 0.f;
        bias[j] = b;
    }
}

// ---------------- prep: features fp32 -> f16, zero-pad rows >= n ----------------
__global__ void conv_feat(const float* __restrict__ F, f16* __restrict__ Fh,
                          int n, long total) {
    long id = (long)blockIdx.x * 256 + threadIdx.x;
    long base = id * 4;
    if (base >= total) return;
    long row = base >> 8;
    float4 v = make_float4(0.f, 0.f, 0.f, 0.f);
    if (row < n) v = *(const float4*)(F + base);
    f16x4v o = { (f16)v.x, (f16)v.y, (f16)v.z, (f16)v.w };
    *(f16x4v*)(Fh + base) = o;
}

// ---------------- prep: CSR row starts (edges sorted by src; every row non-empty) --
__global__ void build_rows(const int* __restrict__ src, int E, int n, int* __restrict__ rs) {
    int e = blockIdx.x * 256 + threadIdx.x;
    if (e == 0) rs[n] = E;
    if (e < E) {
        if (e == 0 || src[e] != src[e-1]) rs[src[e]] = e;
    }
}

// ---------------- fused projection GEMM v3: async global_load_lds staging ----------
// C[m][g] = sum_k Fh[m][k] * Wc[g][k] + bias[g];  scatter by g-region.
// Tile 128x128, BK=32, 4 waves (2x2, 64x64 each), mfma_f32_16x16x32_f16.
// Both tiles staged via global_load_lds(16B) into double-buffered LDS with
// counted vmcnt(4) so next-tile loads stay in flight across barriers (T3/T4).
// LDS layout is LINEAR (gload requirement); the bank swizzle is applied by
// pre-XORing the per-lane GLOBAL source chunk (m173) — read-side decode
// identical to the verified reg-staged version, so mapping is unchanged.
__device__ __forceinline__ int frow(int r) { return (r & 3) ^ ((r >> 2) & 3); }

__device__ __forceinline__ void gload16(const f16* g, f16* l) {
    __builtin_amdgcn_global_load_lds(
        (const __attribute__((address_space(1))) void*)g,
        (__attribute__((address_space(3))) void*)l, 16, 0, 0);
}

__launch_bounds__(256)
__global__ void gemm_fused(const f16* __restrict__ A, const f16* __restrict__ Wc,
                           const float* __restrict__ bias,
                           f16* __restrict__ Qb, f16* __restrict__ Kb, f16* __restrict__ Vb,
                           float* __restrict__ Out, int n) {
    __shared__ uint4 As4[2][512];   // 128 rows x 32 k (f16), double-buffered = 16KB
    __shared__ uint4 Bs4[2][512];   // 128 rows x 32 k, double-buffered = 16KB
    int t = threadIdx.x;
    int lane = t & 63, w = t >> 6;
    int wm = w >> 1, wn = w & 1;
    long m0 = (long)blockIdx.y * 128;
    int n0 = blockIdx.x * 128;

    f32x4 acc[4][4];
    #pragma unroll
    for (int i = 0; i < 4; i++)
        #pragma unroll
        for (int j = 0; j < 4; j++)
            acc[i][j] = (f32x4){0.f, 0.f, 0.f, 0.f};

    int lrow = t >> 2, lc = t & 3;
    int cs = lc ^ frow(lrow);                 // pre-swizzled source chunk (same for row+64)
    const f16* Ag0 = A + (m0 + lrow) * 256 + cs * 8;
    const f16* Ag1 = A + (m0 + 64 + lrow) * 256 + cs * 8;
    const f16* Bg0 = Wc + (long)(n0 + lrow) * 256 + cs * 8;
    const f16* Bg1 = Wc + (long)(n0 + 64 + lrow) * 256 + cs * 8;
    // wave-uniform LDS bases (hardware adds lane*16): slots t and 256+t
    f16* ldsA0 = (f16*)&As4[0][w * 64];
    f16* ldsA1 = (f16*)&As4[0][256 + w * 64];
    f16* ldsB0 = (f16*)&Bs4[0][w * 64];
    f16* ldsB1 = (f16*)&Bs4[0][256 + w * 64];

    int csw = (lane >> 4) ^ (lane & 3) ^ ((lane >> 2) & 3);
    int arow = wm * 64 + (lane & 15);
    int brow = wn * 64 + (lane & 15);

    #define STAGE(kt, b)  do {                              \
        int ko = (kt) * 32, bo = (b) * 512 * 8;             \
        gload16(Ag0 + ko, ldsA0 + bo);                      \
        gload16(Ag1 + ko, ldsA1 + bo);                      \
        gload16(Bg0 + ko, ldsB0 + bo);                      \
        gload16(Bg1 + ko, ldsB1 + bo);                      \
    } while (0)

    STAGE(0, 0);
    for (int kt = 0; kt < 8; ++kt) {
        int b = kt & 1;
        if (kt < 7) {
            STAGE(kt + 1, b ^ 1);                      // issue next tile (stays in flight)
            asm volatile("s_waitcnt vmcnt(4)" ::: "memory");   // current tile landed
        } else {
            asm volatile("s_waitcnt vmcnt(0)" ::: "memory");
        }
        __builtin_amdgcn_s_barrier();                  // all waves: buf b ready
        f16x8 af[4], bf[4];
        const f16x8* Ap = (const f16x8*)As4[b];
        const f16x8* Bp = (const f16x8*)Bs4[b];
        #pragma unroll
        for (int i = 0; i < 4; i++) af[i] = Ap[(arow + i * 16) * 4 + csw];
        #pragma unroll
        for (int j = 0; j < 4; j++) bf[j] = Bp[(brow + j * 16) * 4 + csw];
        #pragma unroll
        for (int i = 0; i < 4; i++)
            #pragma unroll
            for (int j = 0; j < 4; j++)
                acc[i][j] = __builtin_amdgcn_mfma_f32_16x16x32_f16(af[i], bf[j], acc[i][j], 0, 0, 0);
        __builtin_amdgcn_s_barrier();                  // reads done before buf b is re-staged
    }
    #undef STAGE

    // epilogue: C row = (lane>>4)*4 + reg (M), col = lane&15 (N)  [m89-verified]
    #pragma unroll
    for (int i = 0; i < 4; i++) {
        long gmb = m0 + wm * 64 + i * 16 + (lane >> 4) * 4;
        #pragma unroll
        for (int j = 0; j < 4; j++) {
            int gn = n0 + wn * 64 + j * 16 + (lane & 15);
            float bv = bias[gn];
            #pragma unroll
            for (int r = 0; r < 4; r++) {
                long gm = gmb + r;
                if (gm >= n) continue;
                float v = acc[i][j][r] + bv;
                if (gn < 512)       Qb[gm * 512 + gn] = (f16)v;
                else if (gn < 1024) Kb[gm * 512 + (gn - 512)] = (f16)v;
                else if (gn < 1056) Vb[gm * 32 + (gn - 1024)] = (f16)v;
                else if (gn < 1312) Out[gm * 256 + (gn - 1056)] = v;
                // gn in [1312,1408): padding, no write
            }
        }
    }
}

// ---------------- f16x2 dot helper ----------------
__device__ __forceinline__ float fd2(unsigned a, unsigned b, float c) {
#if defined(__has_builtin)
#if __has_builtin(__builtin_amdgcn_fdot2)
    return __builtin_amdgcn_fdot2(__builtin_bit_cast(f16x2, a), __builtin_bit_cast(f16x2, b), c, false);
#else
    f16x2 x = __builtin_bit_cast(f16x2, a), y = __builtin_bit_cast(f16x2, b);
    return c + (float)x[0] * (float)y[0] + (float)x[1] * (float)y[1];
#endif
#else
    f16x2 x = __builtin_bit_cast(f16x2, a), y = __builtin_bit_cast(f16x2, b);
    return c + (float)x[0] * (float)y[0] + (float)x[1] * (float)y[1];
#endif
}

// ---------------- phase A: edge-parallel scores (r6 version — best measured) -------
// 8 lanes per edge (lane = head). nt experiment (r8) REGRESSED: Q rows have real
// L2 reuse across waves/CUs; plain loads + XCD swizzle is the measured optimum
// (~370us, 794MB L2-miss at ~92% of the fill-path wall).
__launch_bounds__(256)
__global__ void edge_scores(const int* __restrict__ srcA, const int* __restrict__ dstA,
                            const f16* __restrict__ Qb, const f16* __restrict__ Kb,
                            f16* __restrict__ sE, int E, int nwg) {
    int bid = blockIdx.x;
    int q = nwg >> 3, r = nwg & 7, xcd = bid & 7, off = bid >> 3;
    int wg = (xcd < r ? xcd * (q + 1) : r * (q + 1) + (xcd - r) * q) + off;
    long id = (long)wg * 256 + threadIdx.x;
    int e = (int)(id >> 3), h = (int)(id & 7);
    if (e >= E) return;
    int s = srcA[e], d = dstA[e];
    const uint4* qp = (const uint4*)(Qb + (size_t)s * 512 + h * 64);
    const uint4* kp = (const uint4*)(Kb + (size_t)d * 512 + h * 64);
    uint4 kv[8], qv[8];
    #pragma unroll
    for (int c = 0; c < 8; c++) kv[c] = kp[c];   // random gather (the fundamental traffic)
    #pragma unroll
    for (int c = 0; c < 8; c++)
        asm volatile("" : "+v"(kv[c].x), "+v"(kv[c].y), "+v"(kv[c].z), "+v"(kv[c].w));
    #pragma unroll
    for (int c = 0; c < 8; c++) qv[c] = qp[c];   // L1/L2-hot stream
    float a0 = 0.f, a1 = 0.f;
    #pragma unroll
    for (int c = 0; c < 8; c += 2) {
        a0 = fd2(qv[c].x,   kv[c].x,   a0);
        a0 = fd2(qv[c].y,   kv[c].y,   a0);
        a0 = fd2(qv[c].z,   kv[c].z,   a0);
        a0 = fd2(qv[c].w,   kv[c].w,   a0);
        a1 = fd2(qv[c+1].x, kv[c+1].x, a1);
        a1 = fd2(qv[c+1].y, kv[c+1].y, a1);
        a1 = fd2(qv[c+1].z, kv[c+1].z, a1);
        a1 = fd2(qv[c+1].w, kv[c+1].w, a1);
    }
    sE[(size_t)e * 8 + h] = (f16)(a0 + a1);   // [e][h], coalesced 128B/wave
}

// ---------------- phase B: row-parallel softmax + MFMA aggregation ----------------
// Wave per row. Pass 1: per-head max. Pass 2: P = exp(s-m) -> LDS (XOR-swizzled);
// out[16h x 32d] = P @ Vgather via 4 MFMAs; denom l = P @ ones via 2 more MFMAs.
__launch_bounds__(256)
__global__ void edge_agg(const int* __restrict__ rs, const int* __restrict__ dstA,
                         const f16* __restrict__ sE, const f16* __restrict__ Vb,
                         float* __restrict__ Out, int n) {
    __shared__ __align__(16) f16 P_lds[4][16][64];
    __shared__ int dS[4][64];
    int w = threadIdx.x >> 6, lane = threadIdx.x & 63;
    int row = blockIdx.x * 4 + w;
    if (row >= n) return;
    int e0 = rs[row], deg = rs[row + 1] - e0;
    {   // zero A-frag rows 8..15 (read by MFMA, results discarded; avoid NaN garbage)
        f16x8 z = {};
        *(f16x8*)&P_lds[w][8 + (lane >> 3)][(lane & 7) * 8] = z;
    }
    // pass 1: global per-head max
    float pm[8];
    #pragma unroll
    for (int h = 0; h < 8; h++) pm[h] = -1e30f;
    for (int base = 0; base < deg; base += 64) {
        bool act = lane < deg - base;
        f16x8 s8 = {};
        if (act) s8 = *(const f16x8*)(sE + (size_t)(e0 + base + lane) * 8);
        #pragma unroll
        for (int h = 0; h < 8; h++)
            pm[h] = fmaxf(pm[h], act ? (float)s8[h] : -1e30f);
    }
    float m[8];
    #pragma unroll
    for (int h = 0; h < 8; h++) {
        float v = pm[h];
        #pragma unroll
        for (int off = 1; off < 64; off <<= 1) v = fmaxf(v, __shfl_xor(v, off));
        m[h] = v;
    }
    // pass 2: P, V-MFMA, ones-MFMA (denominator)
    f32x4 acc0 = {}, acc1 = {}, accl = {};
    int ec0 = (lane >> 4) * 8, h_a = lane & 15, hsel = (lane >> 4) & 1;
    f16x8 ones;
    #pragma unroll
    for (int j = 0; j < 8; j++) ones[j] = (f16)1.f;
    for (int base = 0; base < deg; base += 64) {
        int nE = deg - base; if (nE > 64) nE = 64;
        bool act = lane < nE;
        int d = dstA[e0 + base + (act ? lane : 0)];
        dS[w][lane] = d;
        f16x8 s8 = {};
        if (act) s8 = *(const f16x8*)(sE + (size_t)(e0 + base + lane) * 8);
        #pragma unroll
        for (int h = 0; h < 8; h++) {
            float p = act ? __expf((float)s8[h] - m[h]) : 0.f;
            P_lds[w][h][lane ^ (h << 3)] = (f16)p;
        }
        // A-frags: P[h][k], k = ks*32 + ec0 + j (XOR-decoded contiguous b128)
        f16x8 a0 = *(const f16x8*)&P_lds[w][h_a][(ec0)      ^ ((h_a & 7) << 3)];
        f16x8 a1 = *(const f16x8*)&P_lds[w][h_a][(32 + ec0) ^ ((h_a & 7) << 3)];
        // B-frags: V[e][dim], dim = nh*16 + (lane&15)
        f16x8 bf0a, bf0b, bf1a, bf1b;
        #pragma unroll
        for (int j = 0; j < 8; j++) {
            int dd0 = dS[w][ec0 + j];
            int dd1 = dS[w][32 + ec0 + j];
            const f16* vp0 = Vb + (size_t)dd0 * 32 + (lane & 15);
            const f16* vp1 = Vb + (size_t)dd1 * 32 + (lane & 15);
            bf0a[j] = vp0[0];  bf0b[j] = vp0[16];
            bf1a[j] = vp1[0];  bf1b[j] = vp1[16];
        }
        acc0 = __builtin_amdgcn_mfma_f32_16x16x32_f16(a0, bf0a, acc0, 0, 0, 0);
        acc0 = __builtin_amdgcn_mfma_f32_16x16x32_f16(a1, bf1a, acc0, 0, 0, 0);
        acc1 = __builtin_amdgcn_mfma_f32_16x16x32_f16(a0, bf0b, acc1, 0, 0, 0);
        acc1 = __builtin_amdgcn_mfma_f32_16x16x32_f16(a1, bf1b, acc1, 0, 0, 0);
        accl = __builtin_amdgcn_mfma_f32_16x16x32_f16(a0, ones, accl, 0, 0, 0);
        accl = __builtin_amdgcn_mfma_f32_16x16x32_f16(a1, ones, accl, 0, 0, 0);
    }
    // epilogue: D row = hsel*4 + r = head, col = lane&15; out dim = h*32 + nh*16 + col
    if (lane < 32) {
        float* op = Out + (size_t)row * 256 + (lane & 15);
        #pragma unroll
        for (int r = 0; r < 4; r++) {
            int h = hsel * 4 + r;
            float inv = 1.f / accl[r];
            op[h * 32]      += acc0[r] * inv;
            op[h * 32 + 16] += acc1[r] * inv;
        }
    }
}

// ---------------- launch ----------------
extern "C" void kernel_launch(void* const* d_in, const int* in_sizes, int n_in,
                              void* d_out, int out_size, void* d_ws, size_t ws_size,
                              hipStream_t stream) {
    const float* F  = (const float*)d_in[0];
    const int*   ei = (const int*)d_in[1];
    const float* Wq = (const float*)d_in[2];
    const float* bq = (const float*)d_in[3];
    const float* Wk = (const float*)d_in[4];
    const float* bk = (const float*)d_in[5];
    const float* Ww = (const float*)d_in[6];
    const float* bw = (const float*)d_in[7];
    const float* Wb = (const float*)d_in[8];
    const float* bb = (const float*)d_in[9];
    int n = in_sizes[0] / 256;       // 50000
    int E = in_sizes[1] / 2;
    const int* srcA = ei;
    const int* dstA = ei + E;
    int n_pad = (n + 127) & ~127;

    // workspace carve-out (~133 MB); Fh and sE alias (Fh dead after gemm_fused)
    char* wp = (char*)d_ws;
    auto alloc = [&](size_t bytes) { void* p = wp; wp += (bytes + 255) & ~255ull; return p; };
    size_t fhB = (size_t)n_pad * 256 * 2;
    size_t seB = (size_t)E * 8 * 2;
    void*  reg0 = alloc(fhB > seB ? fhB : seB);
    f16*   Fh   = (f16*)reg0;
    f16*   sE   = (f16*)reg0;
    f16*   Wc   = (f16*)alloc((size_t)WC_PAD * 256 * 2);
    float* bias = (float*)alloc((size_t)WC_PAD * 4);
    f16*   Qb   = (f16*)alloc((size_t)n * 512 * 2);
    f16*   Kb   = (f16*)alloc((size_t)n * 512 * 2);
    f16*   Vb   = (f16*)alloc((size_t)n * 32 * 2);
    int*   rs   = (int*)alloc((size_t)(n + 1) * 4);
    float* Out  = (float*)d_out;

    prep_weights<<<WC_PAD, 256, 0, stream>>>(Wq, bq, Wk, bk, Ww, bw, Wb, bb, Wc, bias);
    long totalF = (long)n_pad * 256;
    conv_feat<<<(int)((totalF / 4 + 255) / 256), 256, 0, stream>>>(F, Fh, n, totalF);
    build_rows<<<(E + 255) / 256, 256, 0, stream>>>(srcA, E, n, rs);
    dim3 g(WC_PAD / 128, n_pad / 128);   // N fastest: A-panel L2-reuse, B L2-resident
    gemm_fused<<<g, 256, 0, stream>>>(Fh, Wc, bias, Qb, Kb, Vb, Out, n);
    int nwg = (int)(((long)E * 8 + 255) / 256);
    edge_scores<<<nwg, 256, 0, stream>>>(srcA, dstA, Qb, Kb, sE, E, nwg);
    edge_agg<<<(n + 3) / 4, 256, 0, stream>>>(rs, dstA, sE, Vb, Out, n);
}

// Round 11
// 536.305 us; speedup vs baseline: 1.0896x; 1.0014x over previous
//
#include <hip/hip_runtime.h>
#include <hip/hip_fp16.h>

typedef _Float16 f16;
typedef _Float16 f16x2 __attribute__((ext_vector_type(2)));
typedef _Float16 f16x4v __attribute__((ext_vector_type(4)));
typedef _Float16 f16x8 __attribute__((ext_vector_type(8)));
typedef float f32x4 __attribute__((ext_vector_type(4)));

// Combined projection: rows 0..511 = Wq (8 heads x 64), 512..1023 = Wk,
// 1024..1055 = Ww (V), 1056..1311 = Wb (output). Padded to 1408 rows (128-mult).
#define WC_ROWS 1312
#define WC_PAD 1408

// ---------------- prep: combined weight matrix (f16) + bias (f32) ----------------
__global__ void prep_weights(const float* __restrict__ Wq, const float* __restrict__ bq,
                             const float* __restrict__ Wk, const float* __restrict__ bk,
                             const float* __restrict__ Ww, const float* __restrict__ bw,
                             const float* __restrict__ Wb, const float* __restrict__ bb,
                             f16* __restrict__ Wc, float* __restrict__ bias) {
    int id = blockIdx.x * 256 + threadIdx.x;   // WC_PAD*256 threads
    int j = id >> 8, k = id & 255;
    if (j >= WC_PAD) return;
    float v;
    if (j < 512)       v = Wq[j*256 + k];          // Wq flat [8,64,256]: row h*64+d == j
    else if (j < 1024) v = Wk[(j-512)*256 + k];
    else if (j < 1056) v = Ww[(j-1024)*256 + k];
    else if (j < 1312) v = Wb[(j-1056)*256 + k];
    else               v = 0.f;
    Wc[j*256 + k] = (f16)v;
    if (k == 0) {
        float b;
        if (j < 512)       b = bq[j];
        else if (j < 1024) b = bk[j-512];
        else if (j < 1056) b = bw[j-1024];
        else if (j < 1312) b = bb[j-1056];
        else               b = 0.f;
        bias[j] = b;
    }
}

// ---------------- prep: features fp32 -> f16, zero-pad rows >= n ----------------
__global__ void conv_feat(const float* __restrict__ F, f16* __restrict__ Fh,
                          int n, long total) {
    long id = (long)blockIdx.x * 256 + threadIdx.x;
    long base = id * 4;
    if (base >= total) return;
    long row = base >> 8;
    float4 v = make_float4(0.f, 0.f, 0.f, 0.f);
    if (row < n) v = *(const float4*)(F + base);
    f16x4v o = { (f16)v.x, (f16)v.y, (f16)v.z, (f16)v.w };
    *(f16x4v*)(Fh + base) = o;
}

// ---------------- prep: CSR row starts (edges sorted by src; every row non-empty) --
__global__ void build_rows(const int* __restrict__ src, int E, int n, int* __restrict__ rs) {
    int e = blockIdx.x * 256 + threadIdx.x;
    if (e == 0) rs[n] = E;
    if (e < E) {
        if (e == 0 || src[e] != src[e-1]) rs[src[e]] = e;
    }
}

// ---------------- fused projection GEMM v3: async global_load_lds staging ----------
// C[m][g] = sum_k Fh[m][k] * Wc[g][k] + bias[g];  scatter by g-region.
// Tile 128x128, BK=32, 4 waves (2x2, 64x64 each), mfma_f32_16x16x32_f16.
// Both tiles staged via global_load_lds(16B) into double-buffered LDS with
// counted vmcnt(4) so next-tile loads stay in flight across barriers (T3/T4).
// LDS is LINEAR (gload requirement); bank swizzle applied by pre-XORing the
// per-lane GLOBAL source chunk (m173) — read-side decode unchanged.
__device__ __forceinline__ int frow(int r) { return (r & 3) ^ ((r >> 2) & 3); }

__device__ __forceinline__ void gload16(const f16* g, f16* l) {
    __builtin_amdgcn_global_load_lds(
        (const __attribute__((address_space(1))) void*)g,
        (__attribute__((address_space(3))) void*)l, 16, 0, 0);
}

__launch_bounds__(256)
__global__ void gemm_fused(const f16* __restrict__ A, const f16* __restrict__ Wc,
                           const float* __restrict__ bias,
                           f16* __restrict__ Qb, f16* __restrict__ Kb, f16* __restrict__ Vb,
                           float* __restrict__ Out, int n) {
    __shared__ uint4 As4[2][512];   // 128 rows x 32 k (f16), double-buffered = 16KB
    __shared__ uint4 Bs4[2][512];   // 128 rows x 32 k, double-buffered = 16KB
    int t = threadIdx.x;
    int lane = t & 63, w = t >> 6;
    int wm = w >> 1, wn = w & 1;
    long m0 = (long)blockIdx.y * 128;
    int n0 = blockIdx.x * 128;

    f32x4 acc[4][4];
    #pragma unroll
    for (int i = 0; i < 4; i++)
        #pragma unroll
        for (int j = 0; j < 4; j++)
            acc[i][j] = (f32x4){0.f, 0.f, 0.f, 0.f};

    int lrow = t >> 2, lc = t & 3;
    int cs = lc ^ frow(lrow);                 // pre-swizzled source chunk (same for row+64)
    const f16* Ag0 = A + (m0 + lrow) * 256 + cs * 8;
    const f16* Ag1 = A + (m0 + 64 + lrow) * 256 + cs * 8;
    const f16* Bg0 = Wc + (long)(n0 + lrow) * 256 + cs * 8;
    const f16* Bg1 = Wc + (long)(n0 + 64 + lrow) * 256 + cs * 8;
    // wave-uniform LDS bases (hardware adds lane*16): slots t and 256+t
    f16* ldsA0 = (f16*)&As4[0][w * 64];
    f16* ldsA1 = (f16*)&As4[0][256 + w * 64];
    f16* ldsB0 = (f16*)&Bs4[0][w * 64];
    f16* ldsB1 = (f16*)&Bs4[0][256 + w * 64];

    int csw = (lane >> 4) ^ (lane & 3) ^ ((lane >> 2) & 3);
    int arow = wm * 64 + (lane & 15);
    int brow = wn * 64 + (lane & 15);

    #define STAGE(kt, b)  do {                              \
        int ko = (kt) * 32, bo = (b) * 512 * 8;             \
        gload16(Ag0 + ko, ldsA0 + bo);                      \
        gload16(Ag1 + ko, ldsA1 + bo);                      \
        gload16(Bg0 + ko, ldsB0 + bo);                      \
        gload16(Bg1 + ko, ldsB1 + bo);                      \
    } while (0)

    STAGE(0, 0);
    for (int kt = 0; kt < 8; ++kt) {
        int b = kt & 1;
        if (kt < 7) {
            STAGE(kt + 1, b ^ 1);                      // issue next tile (stays in flight)
            asm volatile("s_waitcnt vmcnt(4)" ::: "memory");   // current tile landed
        } else {
            asm volatile("s_waitcnt vmcnt(0)" ::: "memory");
        }
        __builtin_amdgcn_s_barrier();                  // all waves: buf b ready
        f16x8 af[4], bf[4];
        const f16x8* Ap = (const f16x8*)As4[b];
        const f16x8* Bp = (const f16x8*)Bs4[b];
        #pragma unroll
        for (int i = 0; i < 4; i++) af[i] = Ap[(arow + i * 16) * 4 + csw];
        #pragma unroll
        for (int j = 0; j < 4; j++) bf[j] = Bp[(brow + j * 16) * 4 + csw];
        #pragma unroll
        for (int i = 0; i < 4; i++)
            #pragma unroll
            for (int j = 0; j < 4; j++)
                acc[i][j] = __builtin_amdgcn_mfma_f32_16x16x32_f16(af[i], bf[j], acc[i][j], 0, 0, 0);
        __builtin_amdgcn_s_barrier();                  // reads done before buf b is re-staged
    }
    #undef STAGE

    // epilogue: C row = (lane>>4)*4 + reg (M), col = lane&15 (N)  [m89-verified]
    #pragma unroll
    for (int i = 0; i < 4; i++) {
        long gmb = m0 + wm * 64 + i * 16 + (lane >> 4) * 4;
        #pragma unroll
        for (int j = 0; j < 4; j++) {
            int gn = n0 + wn * 64 + j * 16 + (lane & 15);
            float bv = bias[gn];
            #pragma unroll
            for (int r = 0; r < 4; r++) {
                long gm = gmb + r;
                if (gm >= n) continue;
                float v = acc[i][j][r] + bv;
                if (gn < 512)       Qb[gm * 512 + gn] = (f16)v;
                else if (gn < 1024) Kb[gm * 512 + (gn - 512)] = (f16)v;
                else if (gn < 1056) Vb[gm * 32 + (gn - 1024)] = (f16)v;
                else if (gn < 1312) Out[gm * 256 + (gn - 1056)] = v;
                // gn in [1312,1408): padding, no write
            }
        }
    }
}

// ---------------- f16x2 dot helper ----------------
__device__ __forceinline__ float fd2(unsigned a, unsigned b, float c) {
#if defined(__has_builtin)
#if __has_builtin(__builtin_amdgcn_fdot2)
    return __builtin_amdgcn_fdot2(__builtin_bit_cast(f16x2, a), __builtin_bit_cast(f16x2, b), c, false);
#else
    f16x2 x = __builtin_bit_cast(f16x2, a), y = __builtin_bit_cast(f16x2, b);
    return c + (float)x[0] * (float)y[0] + (float)x[1] * (float)y[1];
#endif
#else
    f16x2 x = __builtin_bit_cast(f16x2, a), y = __builtin_bit_cast(f16x2, b);
    return c + (float)x[0] * (float)y[0] + (float)x[1] * (float)y[1];
#endif
}

// ---------------- phase A: edge-parallel scores, HEAD-PHASED mapping ---------------
// One thread per (edge, head) as before, but h = bid&7 / e = (bid>>3)*256+tid:
// with round-robin block->XCD dispatch, XCD x streams ALL edges for head x only.
// Head h touches only the 128B line at offset h*128 of each 1KB K row, so the
// per-XCD L2 working set drops 51MB -> 6.4MB (~fits the 4MB L2). Inner loop,
// per-XCD instruction count, and src-sorted Q locality are unchanged.
__launch_bounds__(256)
__global__ void edge_scores(const int* __restrict__ srcA, const int* __restrict__ dstA,
                            const f16* __restrict__ Qb, const f16* __restrict__ Kb,
                            f16* __restrict__ sE, int E) {
    int bid = blockIdx.x;
    int h = bid & 7;                          // head = XCD (round-robin dispatch)
    int e = (bid >> 3) * 256 + threadIdx.x;   // contiguous src-sorted edge stream
    if (e >= E) return;
    int s = srcA[e], d = dstA[e];
    const uint4* qp = (const uint4*)(Qb + (size_t)s * 512 + h * 64);
    const uint4* kp = (const uint4*)(Kb + (size_t)d * 512 + h * 64);
    uint4 kv[8], qv[8];
    #pragma unroll
    for (int c = 0; c < 8; c++) kv[c] = kp[c];   // random gather (the fundamental traffic)
    #pragma unroll
    for (int c = 0; c < 8; c++)
        asm volatile("" : "+v"(kv[c].x), "+v"(kv[c].y), "+v"(kv[c].z), "+v"(kv[c].w));
    #pragma unroll
    for (int c = 0; c < 8; c++) qv[c] = qp[c];   // L1/L2-hot stream
    float a0 = 0.f, a1 = 0.f;
    #pragma unroll
    for (int c = 0; c < 8; c += 2) {
        a0 = fd2(qv[c].x,   kv[c].x,   a0);
        a0 = fd2(qv[c].y,   kv[c].y,   a0);
        a0 = fd2(qv[c].z,   kv[c].z,   a0);
        a0 = fd2(qv[c].w,   kv[c].w,   a0);
        a1 = fd2(qv[c+1].x, kv[c+1].x, a1);
        a1 = fd2(qv[c+1].y, kv[c+1].y, a1);
        a1 = fd2(qv[c+1].z, kv[c+1].z, a1);
        a1 = fd2(qv[c+1].w, kv[c+1].w, a1);
    }
    sE[(size_t)e * 8 + h] = (f16)(a0 + a1);
}

// ---------------- phase B: row-parallel softmax + MFMA aggregation (r9-exact) ------
// Wave per row. Pass 1: per-head max. Pass 2: P = exp(s-m) -> LDS (XOR-swizzled);
// out[16h x 32d] = P @ Vgather via 4 MFMAs; denom l = P @ ones via 2 more MFMAs.
// NOTE: r10's single-pass online-softmax variant tripped the determinism tripwire;
// reverted to this two-pass version which passed it.
__launch_bounds__(256)
__global__ void edge_agg(const int* __restrict__ rs, const int* __restrict__ dstA,
                         const f16* __restrict__ sE, const f16* __restrict__ Vb,
                         float* __restrict__ Out, int n) {
    __shared__ __align__(16) f16 P_lds[4][16][64];
    __shared__ int dS[4][64];
    int w = threadIdx.x >> 6, lane = threadIdx.x & 63;
    int row = blockIdx.x * 4 + w;
    if (row >= n) return;
    int e0 = rs[row], deg = rs[row + 1] - e0;
    {   // zero A-frag rows 8..15 (read by MFMA, results discarded; avoid NaN garbage)
        f16x8 z = {};
        *(f16x8*)&P_lds[w][8 + (lane >> 3)][(lane & 7) * 8] = z;
    }
    // pass 1: global per-head max
    float pm[8];
    #pragma unroll
    for (int h = 0; h < 8; h++) pm[h] = -1e30f;
    for (int base = 0; base < deg; base += 64) {
        bool act = lane < deg - base;
        f16x8 s8 = {};
        if (act) s8 = *(const f16x8*)(sE + (size_t)(e0 + base + lane) * 8);
        #pragma unroll
        for (int h = 0; h < 8; h++)
            pm[h] = fmaxf(pm[h], act ? (float)s8[h] : -1e30f);
    }
    float m[8];
    #pragma unroll
    for (int h = 0; h < 8; h++) {
        float v = pm[h];
        #pragma unroll
        for (int off = 1; off < 64; off <<= 1) v = fmaxf(v, __shfl_xor(v, off));
        m[h] = v;
    }
    // pass 2: P, V-MFMA, ones-MFMA (denominator)
    f32x4 acc0 = {}, acc1 = {}, accl = {};
    int ec0 = (lane >> 4) * 8, h_a = lane & 15, hsel = (lane >> 4) & 1;
    f16x8 ones;
    #pragma unroll
    for (int j = 0; j < 8; j++) ones[j] = (f16)1.f;
    for (int base = 0; base < deg; base += 64) {
        int nE = deg - base; if (nE > 64) nE = 64;
        bool act = lane < nE;
        int d = dstA[e0 + base + (act ? lane : 0)];
        dS[w][lane] = d;
        f16x8 s8 = {};
        if (act) s8 = *(const f16x8*)(sE + (size_t)(e0 + base + lane) * 8);
        #pragma unroll
        for (int h = 0; h < 8; h++) {
            float p = act ? __expf((float)s8[h] - m[h]) : 0.f;
            P_lds[w][h][lane ^ (h << 3)] = (f16)p;
        }
        // A-frags: P[h][k], k = ks*32 + ec0 + j (XOR-decoded contiguous b128)
        f16x8 a0 = *(const f16x8*)&P_lds[w][h_a][(ec0)      ^ ((h_a & 7) << 3)];
        f16x8 a1 = *(const f16x8*)&P_lds[w][h_a][(32 + ec0) ^ ((h_a & 7) << 3)];
        // B-frags: V[e][dim], dim = nh*16 + (lane&15)
        f16x8 bf0a, bf0b, bf1a, bf1b;
        #pragma unroll
        for (int j = 0; j < 8; j++) {
            int dd0 = dS[w][ec0 + j];
            int dd1 = dS[w][32 + ec0 + j];
            const f16* vp0 = Vb + (size_t)dd0 * 32 + (lane & 15);
            const f16* vp1 = Vb + (size_t)dd1 * 32 + (lane & 15);
            bf0a[j] = vp0[0];  bf0b[j] = vp0[16];
            bf1a[j] = vp1[0];  bf1b[j] = vp1[16];
        }
        acc0 = __builtin_amdgcn_mfma_f32_16x16x32_f16(a0, bf0a, acc0, 0, 0, 0);
        acc0 = __builtin_amdgcn_mfma_f32_16x16x32_f16(a1, bf1a, acc0, 0, 0, 0);
        acc1 = __builtin_amdgcn_mfma_f32_16x16x32_f16(a0, bf0b, acc1, 0, 0, 0);
        acc1 = __builtin_amdgcn_mfma_f32_16x16x32_f16(a1, bf1b, acc1, 0, 0, 0);
        accl = __builtin_amdgcn_mfma_f32_16x16x32_f16(a0, ones, accl, 0, 0, 0);
        accl = __builtin_amdgcn_mfma_f32_16x16x32_f16(a1, ones, accl, 0, 0, 0);
    }
    // epilogue: D row = hsel*4 + r = head, col = lane&15; out dim = h*32 + nh*16 + col
    if (lane < 32) {
        float* op = Out + (size_t)row * 256 + (lane & 15);
        #pragma unroll
        for (int r = 0; r < 4; r++) {
            int h = hsel * 4 + r;
            float inv = 1.f / accl[r];
            op[h * 32]      += acc0[r] * inv;
            op[h * 32 + 16] += acc1[r] * inv;
        }
    }
}

// ---------------- launch ----------------
extern "C" void kernel_launch(void* const* d_in, const int* in_sizes, int n_in,
                              void* d_out, int out_size, void* d_ws, size_t ws_size,
                              hipStream_t stream) {
    const float* F  = (const float*)d_in[0];
    const int*   ei = (const int*)d_in[1];
    const float* Wq = (const float*)d_in[2];
    const float* bq = (const float*)d_in[3];
    const float* Wk = (const float*)d_in[4];
    const float* bk = (const float*)d_in[5];
    const float* Ww = (const float*)d_in[6];
    const float* bw = (const float*)d_in[7];
    const float* Wb = (const float*)d_in[8];
    const float* bb = (const float*)d_in[9];
    int n = in_sizes[0] / 256;       // 50000
    int E = in_sizes[1] / 2;
    const int* srcA = ei;
    const int* dstA = ei + E;
    int n_pad = (n + 127) & ~127;

    // workspace carve-out (~133 MB); Fh and sE alias (Fh dead after gemm_fused)
    char* wp = (char*)d_ws;
    auto alloc = [&](size_t bytes) { void* p = wp; wp += (bytes + 255) & ~255ull; return p; };
    size_t fhB = (size_t)n_pad * 256 * 2;
    size_t seB = (size_t)E * 8 * 2;
    void*  reg0 = alloc(fhB > seB ? fhB : seB);
    f16*   Fh   = (f16*)reg0;
    f16*   sE   = (f16*)reg0;
    f16*   Wc   = (f16*)alloc((size_t)WC_PAD * 256 * 2);
    float* bias = (float*)alloc((size_t)WC_PAD * 4);
    f16*   Qb   = (f16*)alloc((size_t)n * 512 * 2);
    f16*   Kb   = (f16*)alloc((size_t)n * 512 * 2);
    f16*   Vb   = (f16*)alloc((size_t)n * 32 * 2);
    int*   rs   = (int*)alloc((size_t)(n + 1) * 4);
    float* Out  = (float*)d_out;

    prep_weights<<<WC_PAD, 256, 0, stream>>>(Wq, bq, Wk, bk, Ww, bw, Wb, bb, Wc, bias);
    long totalF = (long)n_pad * 256;
    conv_feat<<<(int)((totalF / 4 + 255) / 256), 256, 0, stream>>>(F, Fh, n, totalF);
    build_rows<<<(E + 255) / 256, 256, 0, stream>>>(srcA, E, n, rs);
    dim3 g(WC_PAD / 128, n_pad / 128);   // N fastest: A-panel L2-reuse, B L2-resident
    gemm_fused<<<g, 256, 0, stream>>>(Fh, Wc, bias, Qb, Kb, Vb, Out, n);
    int wgph = (E + 255) / 256;          // workgroups per head
    edge_scores<<<8 * wgph, 256, 0, stream>>>(srcA, dstA, Qb, Kb, sE, E);
    edge_agg<<<(n + 3) / 4, 256, 0, stream>>>(rs, dstA, sE, Vb, Out, n);
}